// Round 21
// baseline (108.588 us; speedup 1.0000x reference)
//
#include <hip/hip_runtime.h>
#include <hip/hip_bf16.h>

#define Bc   4
#define Pc   12
#define Nc   4096
#define Hc   64
#define TDc  128
#define Ec   65536
#define BPc  48
#define Gg   6            // bp-slices per XCD group (bp = g + 8*j, j<6)
#define NHc  (Nc*Hc)      // 262144
#define ROWS (BPc*Nc)     // 196608
#define EPSc 1e-5f

typedef float    f32x4 __attribute__((ext_vector_type(4)));
typedef _Float16 f16x2 __attribute__((ext_vector_type(2)));
typedef _Float16 f16x4 __attribute__((ext_vector_type(4)));
typedef _Float16 f16x8 __attribute__((ext_vector_type(8)));

// ---- prep: tproj (bid 0) + gnw/gnb pack (1..1024) + deg clear (1025..1040)
//      + fragment-major f16 weight pre-conversion (1041: layer0, 1042: layer1) ----
__global__ __launch_bounds__(256) void k_prep(const float* __restrict__ timev,
                                              const float* __restrict__ w1, const float* __restrict__ b1,
                                              const float* __restrict__ w2, const float* __restrict__ b2,
                                              float* __restrict__ t_out,
                                              const float* __restrict__ gnw,
                                              const float* __restrict__ gnb,
                                              f16x2* __restrict__ gpack,
                                              int* __restrict__ deg,
                                              const float* __restrict__ cw1,
                                              const float* __restrict__ cw2,
                                              _Float16* __restrict__ wpack) {
    int bid = blockIdx.x;
    int t = threadIdx.x;
    if (bid == 0) {
        __shared__ float s_time[Bc * TDc];
        __shared__ float s_hid[Bc * Hc];
        for (int i = t; i < Bc * TDc; i += 256) s_time[i] = timev[i];
        __syncthreads();
        int b = t >> 6, j = t & 63;
        float acc = b1[j];
        for (int k = 0; k < TDc; ++k) acc = fmaf(s_time[b * TDc + k], w1[j * TDc + k], acc);
        s_hid[b * Hc + j] = fmaxf(acc, 0.f);
        __syncthreads();
        float acc2 = b2[j];
        for (int k = 0; k < Hc; ++k) acc2 = fmaf(s_hid[b * Hc + k], w2[j * Hc + k], acc2);
        t_out[b * Hc + j] = acc2;
    } else if (bid <= 1024) {
        int i = (bid - 1) * 256 + t;
        f16x2 v;
        v.x = (_Float16)gnw[i];
        v.y = (_Float16)gnb[i];
        gpack[i] = v;
    } else if (bid <= 1040) {
        int i = (bid - 1025) * 256 + t;
        deg[i] = 0;
    } else {
        // fragment-major weight pre-conversion (mapping k_mlp's ds_reads expect)
        int layer = bid - 1041;                     // 0 or 1
        const float* wsrc = layer ? cw2 : cw1;
        #pragma unroll
        for (int v4 = 0; v4 < 4; ++v4) {
            int i4 = t + v4 * 256;                  // 0..1023 vector id
            int j  = i4 >> 4;
            int kq = (i4 & 15) * 4;
            f32x4 v = *(const f32x4*)(wsrc + j * Hc + kq);
            int tt = j >> 4, rr = j & 15, kk = kq >> 4, gg = (kq >> 2) & 3;
            int ln = gg * 16 + rr;
            *(f16x4*)&wpack[(((layer * 4 + tt) * 4 + kk) * 64 + ln) * 4] =
                __builtin_convertvector(v, f16x4);
        }
    }
}

// ---------------- degree count ----------------
__global__ void k_deg(const int* __restrict__ col, int* __restrict__ deg) {
    int e = blockIdx.x * 256 + threadIdx.x;
    atomicAdd(&deg[col[e]], 1);
}

// ---------------- exclusive scan over 4096 degrees + dis = deg^-1/2 ----------------
__global__ __launch_bounds__(1024) void k_scan(const int* __restrict__ deg,
                                               int* __restrict__ offs,
                                               int* __restrict__ cursor,
                                               float* __restrict__ dis) {
    __shared__ int part[1024];
    int t = threadIdx.x;
    int d0 = deg[t * 4], d1 = deg[t * 4 + 1], d2 = deg[t * 4 + 2], d3 = deg[t * 4 + 3];
    part[t] = d0 + d1 + d2 + d3;
    __syncthreads();
    for (int off = 1; off < 1024; off <<= 1) {
        int v = (t >= off) ? part[t - off] : 0;
        __syncthreads();
        part[t] += v;
        __syncthreads();
    }
    int base = (t ? part[t - 1] : 0);
    offs[t * 4]     = base;
    offs[t * 4 + 1] = base + d0;
    offs[t * 4 + 2] = base + d0 + d1;
    offs[t * 4 + 3] = base + d0 + d1 + d2;
    if (t == 1023) offs[4096] = part[1023];
    cursor[t * 4]     = base;
    cursor[t * 4 + 1] = base + d0;
    cursor[t * 4 + 2] = base + d0 + d1;
    cursor[t * 4 + 3] = base + d0 + d1 + d2;
    dis[t * 4]     = d0 > 0 ? rsqrtf((float)d0) : 0.f;
    dis[t * 4 + 1] = d1 > 0 ? rsqrtf((float)d1) : 0.f;
    dis[t * 4 + 2] = d2 > 0 ? rsqrtf((float)d2) : 0.f;
    dis[t * 4 + 3] = d3 > 0 ? rsqrtf((float)d3) : 0.f;
}

// ---------------- CSR fill: csr2 = {src, bits(w)} ----------------
__global__ void k_fill(const int* __restrict__ ei, int* __restrict__ cursor,
                       const float* __restrict__ dis,
                       int2* __restrict__ csr2) {
    int e = blockIdx.x * 256 + threadIdx.x;
    int r = ei[e], c = ei[Ec + e];
    int pos = atomicAdd(&cursor[c], 1);
    int2 v;
    v.x = r;
    v.y = __float_as_int(dis[r] * dis[c]);
    csr2[pos] = v;
}

// ---------------- g12 = {gather(gnw), gather(gnb)} interleaved f16x2 ----------------
__global__ __launch_bounds__(256) void k_gw(const int* __restrict__ offs,
                                            const int2* __restrict__ csr2,
                                            const f16x2* __restrict__ gpack,
                                            f16x2* __restrict__ g12) {
    int wv = threadIdx.x >> 6, lane = threadIdx.x & 63;
    int n = __builtin_amdgcn_readfirstlane(blockIdx.x * 4 + wv);
    int s0 = __builtin_amdgcn_readfirstlane(offs[n]);
    int s1 = __builtin_amdgcn_readfirstlane(offs[n + 1]);
    float a0 = 0.f, a1 = 0.f, a2 = 0.f, a3 = 0.f;
    float b0 = 0.f, b1 = 0.f, b2 = 0.f, b3 = 0.f;
    int i = s0;
    for (; i + 4 <= s1; i += 4) {
        int2 e0 = csr2[i], e1 = csr2[i + 1], e2 = csr2[i + 2], e3 = csr2[i + 3];
        f16x2 v0 = gpack[e0.x * Hc + lane];
        f16x2 v1 = gpack[e1.x * Hc + lane];
        f16x2 v2 = gpack[e2.x * Hc + lane];
        f16x2 v3 = gpack[e3.x * Hc + lane];
        float w0 = __int_as_float(e0.y), w1 = __int_as_float(e1.y);
        float w2 = __int_as_float(e2.y), w3 = __int_as_float(e3.y);
        a0 = fmaf(w0, (float)v0.x, a0); b0 = fmaf(w0, (float)v0.y, b0);
        a1 = fmaf(w1, (float)v1.x, a1); b1 = fmaf(w1, (float)v1.y, b1);
        a2 = fmaf(w2, (float)v2.x, a2); b2 = fmaf(w2, (float)v2.y, b2);
        a3 = fmaf(w3, (float)v3.x, a3); b3 = fmaf(w3, (float)v3.y, b3);
    }
    for (; i < s1; ++i) {
        int2 e = csr2[i];
        f16x2 v = gpack[e.x * Hc + lane];
        float w = __int_as_float(e.y);
        a0 = fmaf(w, (float)v.x, a0); b0 = fmaf(w, (float)v.y, b0);
    }
    f16x2 o;
    o.x = (_Float16)((a0 + a1) + (a2 + a3));
    o.y = (_Float16)((b0 + b1) + (b2 + b3));
    g12[n * Hc + lane] = o;
}

// ---------------- MFMA cond-MLP -> Af[g][n][j][h] fp16 (group-transposed); LN1 stats ----
// Zero-tail persistent shape: 512 threads (8 waves), grid = 768 = EXACTLY 3 blocks/CU
// (all co-resident, LDS 35 KB < 160/4) -> no half-empty launch round (round-20's 1536
// blocks ran 4-then-2 per CU, idling half the machine for a third of the kernel).
// Each block: stage weights once (2x global_load_lds/thread from pre-converted wpack),
// then 2 shots of 128 rows through the round-14-proven c-loop (in-loop barrier).
__global__ __launch_bounds__(512) void k_mlp(const float* __restrict__ cond,
                                             const float* __restrict__ x,
                                             const _Float16* __restrict__ wpack,
                                             const float* __restrict__ b1, const float* __restrict__ b2,
                                             const float* __restrict__ gnw,
                                             _Float16* __restrict__ Af, float* __restrict__ part1) {
    __shared__ __align__(16) _Float16 wlds[8192];   // [layer][t][kk][lane][4] = 16 KB
    __shared__ float blds[128];                      // b1 | b2
    __shared__ __align__(16) _Float16 s_h[8][16][72];

    int tid  = threadIdx.x;
    int lane = tid & 63;
    int wv   = tid >> 6;                      // 0..7
    int r = lane & 15, g = lane >> 4;
    int bp = blockIdx.x >> 4;                 // 16 blocks per bp (256 rows each)
    int g4 = bp & 7, j6 = bp >> 3;            // bp = g4 + 8*j6
    int nb16 = (blockIdx.x & 15) * 256;

    // ---- async weight staging: 16 KB linear copy, 2 chunks of 1 KB per wave ----
    #pragma unroll
    for (int i = 0; i < 2; ++i) {
        int c = wv * 2 + i;                   // chunk 0..15, 1024 B each
        __builtin_amdgcn_global_load_lds(
            (const unsigned int*)((const char*)wpack + c * 1024 + lane * 16),
            (unsigned int*)((char*)wlds + c * 1024), 16, 0, 0);
    }
    if (tid < 64) blds[tid] = b1[tid];
    else if (tid < 128) blds[tid] = b2[tid - 64];
    __syncthreads();   // drains vmcnt -> wlds ready

    float s = 0.f, ss = 0.f;
    int nl = lane >> 3, hq = (lane & 7) * 8;
    for (int c = 0; c < 2; ++c) {
        __syncthreads();   // LICM fence: keep weight ds_reads inside the loop
        int row = blockIdx.x * 256 + c * 128 + wv * 16 + r;
        int n   = row & (Nc - 1);
        // issue all global loads for this iteration up front
        f32x4 bcf[4], x4[4], gw4[4];
        #pragma unroll
        for (int kk = 0; kk < 4; ++kk)
            bcf[kk] = *(const f32x4*)(cond + (size_t)row * Hc + kk * 16 + 4 * g);
        #pragma unroll
        for (int t = 0; t < 4; ++t) {
            x4[t]  = *(const f32x4*)(x + (size_t)row * Hc + 16 * t + 4 * g);
            gw4[t] = *(const f32x4*)(gnw + n * Hc + 16 * t + 4 * g);
        }
        f16x4 bc[4];
        #pragma unroll
        for (int kk = 0; kk < 4; ++kk) bc[kk] = __builtin_convertvector(bcf[kk], f16x4);
        // layer 1
        f16x4 hB[4];
        #pragma unroll
        for (int t = 0; t < 4; ++t) {
            f32x4 acc = {0.f, 0.f, 0.f, 0.f};
            #pragma unroll
            for (int kk = 0; kk < 4; ++kk) {
                f16x4 a = *(const f16x4*)&wlds[((t * 4 + kk) * 64 + lane) * 4];
                acc = __builtin_amdgcn_mfma_f32_16x16x16f16(a, bc[kk], acc, 0, 0, 0);
            }
            acc += *(const f32x4*)&blds[16 * t + 4 * g];
            f32x4 h;
            h.x = fmaxf(acc.x, 0.f); h.y = fmaxf(acc.y, 0.f);
            h.z = fmaxf(acc.z, 0.f); h.w = fmaxf(acc.w, 0.f);
            hB[t] = __builtin_convertvector(h, f16x4);
        }
        // layer 2 + bias + residual + gnw scale -> fp16 into per-wave LDS tile
        #pragma unroll
        for (int t = 0; t < 4; ++t) {
            f32x4 acc = {0.f, 0.f, 0.f, 0.f};
            #pragma unroll
            for (int kk = 0; kk < 4; ++kk) {
                f16x4 a = *(const f16x4*)&wlds[((16 + t * 4 + kk) * 64 + lane) * 4];
                acc = __builtin_amdgcn_mfma_f32_16x16x16f16(a, hB[kk], acc, 0, 0, 0);
            }
            f32x4 o = acc + *(const f32x4*)&blds[64 + 16 * t + 4 * g] + x4[t];
            s  += o.x + o.y + o.z + o.w;
            ss += o.x * o.x + o.y * o.y + o.z * o.z + o.w * o.w;
            f32x4 av = o * gw4[t];
            *(f16x4*)&s_h[wv][r][16 * t + 4 * g] = __builtin_convertvector(av, f16x4);
        }
        // transpose read-back: wave-private tile (lgkmcnt ordering, no barrier)
        #pragma unroll
        for (int p = 0; p < 2; ++p) {
            f16x8 v = *(const f16x8*)&s_h[wv][p * 8 + nl][hq];
            int nn = nb16 + c * 128 + wv * 16 + p * 8 + nl;
            *(f16x8*)(Af + (((size_t)g4 * Nc + nn) * Gg + j6) * Hc + hq) = v;
        }
        // per-shot partials (deterministic): idx = blk16*16 + c*8 + wv
        float sl = s, ssl = ss;
        if (c == 0) {
            for (int off = 32; off; off >>= 1) { sl += __shfl_down(sl, off); ssl += __shfl_down(ssl, off); }
            if (lane == 0) {
                int idx = (blockIdx.x & 15) * 16 + wv;   // 0..255 (c=0 half)
                part1[(bp * 256 + idx) * 2]     = sl;
                part1[(bp * 256 + idx) * 2 + 1] = ssl;
            }
            s = 0.f; ss = 0.f;
        }
    }
    for (int off = 32; off; off >>= 1) { s += __shfl_down(s, off); ss += __shfl_down(ss, off); }
    if (lane == 0) {
        int idx = (blockIdx.x & 15) * 16 + 8 + wv;        // c=1 half
        part1[(bp * 256 + idx) * 2]     = s;
        part1[(bp * 256 + idx) * 2 + 1] = ss;
    }
}

// ---------------- finalize LN stats: mu, rsqrt(var+eps) per bp ----------------
__global__ __launch_bounds__(256) void k_finalize(const float* __restrict__ part, int cnt,
                                                  float* __restrict__ murs) {
    int bp = blockIdx.x;
    float s = 0.f, ss = 0.f;
    for (int i = threadIdx.x; i < cnt; i += 256) {
        s  += part[(bp * cnt + i) * 2];
        ss += part[(bp * cnt + i) * 2 + 1];
    }
    __shared__ float ls[4], lss[4];
    for (int off = 32; off; off >>= 1) { s += __shfl_down(s, off); ss += __shfl_down(ss, off); }
    int w = threadIdx.x >> 6, l = threadIdx.x & 63;
    if (l == 0) { ls[w] = s; lss[w] = ss; }
    __syncthreads();
    if (threadIdx.x == 0) {
        s  = ls[0] + ls[1] + ls[2] + ls[3];
        ss = lss[0] + lss[1] + lss[2] + lss[3];
        float mu = s / (float)NHc;
        float var = ss / (float)NHc - mu * mu;
        murs[bp * 2]     = mu;
        murs[bp * 2 + 1] = rsqrtf(var + EPSc);
    }
}

// ---------------- LGConv gather: 1 n x 6 bp per wave, fp16 dwordx4 lanes ----------------
// Af[g][n][j][h]: one XCD group's slice = 3 MB -> fits 4 MB L2 (bid&7 pin).
// Per edge: ONE global_load_dwordx4 serves 6 bp slices. Lanes 48-63 exec-masked.
// Edge loop 8-deep: 8 loads in flight per batch (avg degree 16 -> 2 batches).
__global__ __launch_bounds__(256) void k_gather(const int* __restrict__ offs,
                                                const int2* __restrict__ csr2,
                                                const _Float16* __restrict__ Af,
                                                const f16x2* __restrict__ g12,
                                                const float* __restrict__ murs,
                                                const float* __restrict__ t_in,
                                                _Float16* __restrict__ h2f,
                                                float* __restrict__ part2) {
    int bid = blockIdx.x;
    int g   = bid & 7;
    int seq = bid >> 3;            // 0..1023
    int wv = threadIdx.x >> 6, lane = threadIdx.x & 63;
    int n  = __builtin_amdgcn_readfirstlane(seq * 4 + wv);
    int jj = lane >> 3;            // 0..7 (6,7 masked off)
    int h0 = (lane & 7) * 8;
    int s0 = __builtin_amdgcn_readfirstlane(offs[n]);
    int s1 = __builtin_amdgcn_readfirstlane(offs[n + 1]);

    if (jj < Gg) {
        const _Float16* base = Af + (size_t)g * (Nc * Gg * Hc) + jj * Hc + h0;
        float acc[8];
        #pragma unroll
        for (int i = 0; i < 8; ++i) acc[i] = 0.f;

        int idx = s0;
        for (; idx + 8 <= s1; idx += 8) {
            int2 e0 = csr2[idx],     e1 = csr2[idx + 1];
            int2 e2 = csr2[idx + 2], e3 = csr2[idx + 3];
            int2 e4 = csr2[idx + 4], e5 = csr2[idx + 5];
            int2 e6 = csr2[idx + 6], e7 = csr2[idx + 7];
            f16x8 v0 = *(const f16x8*)(base + (size_t)e0.x * (Gg * Hc));
            f16x8 v1 = *(const f16x8*)(base + (size_t)e1.x * (Gg * Hc));
            f16x8 v2 = *(const f16x8*)(base + (size_t)e2.x * (Gg * Hc));
            f16x8 v3 = *(const f16x8*)(base + (size_t)e3.x * (Gg * Hc));
            f16x8 v4 = *(const f16x8*)(base + (size_t)e4.x * (Gg * Hc));
            f16x8 v5 = *(const f16x8*)(base + (size_t)e5.x * (Gg * Hc));
            f16x8 v6 = *(const f16x8*)(base + (size_t)e6.x * (Gg * Hc));
            f16x8 v7 = *(const f16x8*)(base + (size_t)e7.x * (Gg * Hc));
            float w0 = __int_as_float(e0.y), w1 = __int_as_float(e1.y);
            float w2 = __int_as_float(e2.y), w3 = __int_as_float(e3.y);
            float w4 = __int_as_float(e4.y), w5 = __int_as_float(e5.y);
            float w6 = __int_as_float(e6.y), w7 = __int_as_float(e7.y);
            #pragma unroll
            for (int i = 0; i < 8; ++i) {
                acc[i] = fmaf(w0, (float)v0[i], acc[i]);
                acc[i] = fmaf(w1, (float)v1[i], acc[i]);
                acc[i] = fmaf(w2, (float)v2[i], acc[i]);
                acc[i] = fmaf(w3, (float)v3[i], acc[i]);
                acc[i] = fmaf(w4, (float)v4[i], acc[i]);
                acc[i] = fmaf(w5, (float)v5[i], acc[i]);
                acc[i] = fmaf(w6, (float)v6[i], acc[i]);
                acc[i] = fmaf(w7, (float)v7[i], acc[i]);
            }
        }
        for (; idx + 4 <= s1; idx += 4) {
            int2 e0 = csr2[idx],     e1 = csr2[idx + 1];
            int2 e2 = csr2[idx + 2], e3 = csr2[idx + 3];
            f16x8 v0 = *(const f16x8*)(base + (size_t)e0.x * (Gg * Hc));
            f16x8 v1 = *(const f16x8*)(base + (size_t)e1.x * (Gg * Hc));
            f16x8 v2 = *(const f16x8*)(base + (size_t)e2.x * (Gg * Hc));
            f16x8 v3 = *(const f16x8*)(base + (size_t)e3.x * (Gg * Hc));
            float w0 = __int_as_float(e0.y), w1 = __int_as_float(e1.y);
            float w2 = __int_as_float(e2.y), w3 = __int_as_float(e3.y);
            #pragma unroll
            for (int i = 0; i < 8; ++i) {
                acc[i] = fmaf(w0, (float)v0[i], acc[i]);
                acc[i] = fmaf(w1, (float)v1[i], acc[i]);
                acc[i] = fmaf(w2, (float)v2[i], acc[i]);
                acc[i] = fmaf(w3, (float)v3[i], acc[i]);
            }
        }
        for (; idx < s1; ++idx) {
            int2 e = csr2[idx];
            f16x8 v = *(const f16x8*)(base + (size_t)e.x * (Gg * Hc));
            float w = __int_as_float(e.y);
            #pragma unroll
            for (int i = 0; i < 8; ++i) acc[i] = fmaf(w, (float)v[i], acc[i]);
        }

        int bp = g + 8 * jj;
        int b  = bp / Pc;
        float mu = murs[bp * 2], rs = murs[bp * 2 + 1];
        const _Float16* gp = (const _Float16*)(g12 + n * Hc + h0);
        f16x8 q0 = *(const f16x8*)gp;        // {g1,g2} pairs for h0..h0+3
        f16x8 q1 = *(const f16x8*)(gp + 8);  // pairs for h0+4..h0+7
        f32x4 tta = *(const f32x4*)(t_in + b * Hc + h0);
        f32x4 ttb = *(const f32x4*)(t_in + b * Hc + h0 + 4);
        f32x4 va, vb;
        va.x = rs * (acc[0] - mu * (float)q0[0]) + (float)q0[1] + tta.x;
        va.y = rs * (acc[1] - mu * (float)q0[2]) + (float)q0[3] + tta.y;
        va.z = rs * (acc[2] - mu * (float)q0[4]) + (float)q0[5] + tta.z;
        va.w = rs * (acc[3] - mu * (float)q0[6]) + (float)q0[7] + tta.w;
        vb.x = rs * (acc[4] - mu * (float)q1[0]) + (float)q1[1] + ttb.x;
        vb.y = rs * (acc[5] - mu * (float)q1[2]) + (float)q1[3] + ttb.y;
        vb.z = rs * (acc[6] - mu * (float)q1[4]) + (float)q1[5] + ttb.z;
        vb.w = rs * (acc[7] - mu * (float)q1[6]) + (float)q1[7] + ttb.w;

        float s  = (va.x + va.y) + (va.z + va.w) + (vb.x + vb.y) + (vb.z + vb.w);
        float ss = va.x * va.x + va.y * va.y + va.z * va.z + va.w * va.w
                 + vb.x * vb.x + vb.y * vb.y + vb.z * vb.z + vb.w * vb.w;
        #pragma unroll
        for (int m = 4; m; m >>= 1) { s += __shfl_xor(s, m); ss += __shfl_xor(ss, m); }

        f16x8 hv;
        hv[0] = (_Float16)va.x; hv[1] = (_Float16)va.y;
        hv[2] = (_Float16)va.z; hv[3] = (_Float16)va.w;
        hv[4] = (_Float16)vb.x; hv[5] = (_Float16)vb.y;
        hv[6] = (_Float16)vb.z; hv[7] = (_Float16)vb.w;
        *(f16x8*)(h2f + (size_t)bp * NHc + n * Hc + h0) = hv;
        if ((lane & 7) == 0) {
            part2[((size_t)bp * Nc + n) * 2]     = s;
            part2[((size_t)bp * Nc + n) * 2 + 1] = ss;
        }
    }
}

// ---------------- apply LN2 + 1x1 conv over P (h2 fp16 in ws) ----------------
__global__ __launch_bounds__(256) void k_conv(const _Float16* __restrict__ h2f,
                                              const float* __restrict__ murs,
                                              const float* __restrict__ tnw, const float* __restrict__ tnb,
                                              const float* __restrict__ cw, const float* __restrict__ cb,
                                              float* __restrict__ out) {
    int tid = blockIdx.x * 256 + threadIdx.x;  // B * NHc/4 threads
    int b  = tid >> 16;           // / (NHc/4)
    int i4 = tid & 65535;
    size_t e0 = (size_t)i4 * 4;
    float4 w4 = *(const float4*)(tnw + e0);
    float4 b4 = *(const float4*)(tnb + e0);
    float v[Pc][4];
    #pragma unroll
    for (int p = 0; p < Pc; ++p) {
        int bp = b * Pc + p;
        float mu = murs[bp * 2], rs = murs[bp * 2 + 1];
        f16x4 h = *(const f16x4*)(h2f + (size_t)bp * NHc + e0);
        v[p][0] = ((float)h.x - mu) * rs * w4.x + b4.x;
        v[p][1] = ((float)h.y - mu) * rs * w4.y + b4.y;
        v[p][2] = ((float)h.z - mu) * rs * w4.z + b4.z;
        v[p][3] = ((float)h.w - mu) * rs * w4.w + b4.w;
    }
    #pragma unroll
    for (int q = 0; q < Pc; ++q) {
        float cbq = cb[q];
        float o0 = cbq, o1 = cbq, o2 = cbq, o3 = cbq;
        #pragma unroll
        for (int p = 0; p < Pc; ++p) {
            float wqp = cw[q * Pc + p];
            o0 = fmaf(v[p][0], wqp, o0);
            o1 = fmaf(v[p][1], wqp, o1);
            o2 = fmaf(v[p][2], wqp, o2);
            o3 = fmaf(v[p][3], wqp, o3);
        }
        float4 o = {o0, o1, o2, o3};
        *(float4*)(out + (size_t)(b * Pc + q) * NHc + e0) = o;
    }
}

extern "C" void kernel_launch(void* const* d_in, const int* in_sizes, int n_in,
                              void* d_out, int out_size, void* d_ws, size_t ws_size,
                              hipStream_t stream) {
    (void)in_sizes; (void)n_in; (void)out_size; (void)ws_size;
    const float* x     = (const float*)d_in[0];
    const int*   ei    = (const int*)  d_in[1];
    const float* timev = (const float*)d_in[2];
    const float* cond  = (const float*)d_in[3];
    const float* tp_w1 = (const float*)d_in[4];
    const float* tp_b1 = (const float*)d_in[5];
    const float* tp_w2 = (const float*)d_in[6];
    const float* tp_b2 = (const float*)d_in[7];
    const float* cp_w1 = (const float*)d_in[8];
    const float* cp_b1 = (const float*)d_in[9];
    const float* cp_w2 = (const float*)d_in[10];
    const float* cp_b2 = (const float*)d_in[11];
    const float* gn_w  = (const float*)d_in[12];
    const float* gn_b  = (const float*)d_in[13];
    const float* tn_w  = (const float*)d_in[14];
    const float* tn_b  = (const float*)d_in[15];
    const float* cw    = (const float*)d_in[16];
    const float* cb    = (const float*)d_in[17];
    float* out = (float*)d_out;

    char* w = (char*)d_ws;
    size_t off = 0;
    auto alloc = [&](size_t bytes) {
        void* p = w + off;
        off = (off + bytes + 255) & ~(size_t)255;
        return p;
    };
    _Float16* Af   = (_Float16*)alloc((size_t)ROWS * Hc * sizeof(_Float16)); // 25 MB
    _Float16* h2f  = (_Float16*)alloc((size_t)ROWS * Hc * sizeof(_Float16)); // 25 MB
    float* part1   = (float*)alloc((size_t)BPc * 256 * 2 * 4);
    float* part2   = (float*)alloc((size_t)BPc * Nc * 2 * 4);
    float* murs1   = (float*)alloc(96 * 4);
    float* murs2   = (float*)alloc(96 * 4);
    float* t_ws    = (float*)alloc(256 * 4);
    float* dis     = (float*)alloc(Nc * 4);
    int2*  csr2    = (int2*)alloc((size_t)Ec * 8);
    f16x2* g12     = (f16x2*)alloc((size_t)NHc * 4);
    f16x2* gpack   = (f16x2*)alloc((size_t)NHc * 4);
    _Float16* wpack = (_Float16*)alloc(8192 * sizeof(_Float16));  // 16 KB frag-major
    int*   deg     = (int*)alloc(Nc * 4);
    int*   offs    = (int*)alloc((Nc + 1) * 4);
    int*   cursor  = (int*)alloc(Nc * 4);

    k_prep<<<1043, 256, 0, stream>>>(timev, tp_w1, tp_b1, tp_w2, tp_b2, t_ws,
                                     gn_w, gn_b, gpack, deg, cp_w1, cp_w2, wpack);
    k_deg<<<Ec / 256, 256, 0, stream>>>(ei + Ec, deg);
    k_scan<<<1, 1024, 0, stream>>>(deg, offs, cursor, dis);
    k_fill<<<Ec / 256, 256, 0, stream>>>(ei, cursor, dis, csr2);
    k_gw<<<Nc / 4, 256, 0, stream>>>(offs, csr2, gpack, g12);
    k_mlp<<<ROWS / 256, 512, 0, stream>>>(cond, x, wpack, cp_b1, cp_b2, gn_w,
                                          Af, part1);
    k_finalize<<<BPc, 256, 0, stream>>>(part1, 256, murs1);
    k_gather<<<8 * 1024, 256, 0, stream>>>(offs, csr2, Af, g12,
                                           murs1, t_ws, h2f, part2);
    k_finalize<<<BPc, 256, 0, stream>>>(part2, Nc, murs2);
    k_conv<<<(Bc * NHc / 4) / 256, 256, 0, stream>>>(h2f, murs2, tn_w, tn_b, cw, cb, out);
}

// Round 22
// 106.711 us; speedup vs baseline: 1.0176x; 1.0176x over previous
//
#include <hip/hip_runtime.h>
#include <hip/hip_bf16.h>

#define Bc   4
#define Pc   12
#define Nc   4096
#define Hc   64
#define TDc  128
#define Ec   65536
#define BPc  48
#define Gg   6            // bp-slices per XCD group (bp = g + 8*j, j<6)
#define NHc  (Nc*Hc)      // 262144
#define ROWS (BPc*Nc)     // 196608
#define EPSc 1e-5f

typedef float    f32x4 __attribute__((ext_vector_type(4)));
typedef _Float16 f16x2 __attribute__((ext_vector_type(2)));
typedef _Float16 f16x4 __attribute__((ext_vector_type(4)));
typedef _Float16 f16x8 __attribute__((ext_vector_type(8)));

// ---- prep: tproj (bid 0) + gnw/gnb pack (1..1024) + deg clear (1025..1040)
//      + fragment-major f16 weight pre-conversion (1041: layer0, 1042: layer1) ----
__global__ __launch_bounds__(256) void k_prep(const float* __restrict__ timev,
                                              const float* __restrict__ w1, const float* __restrict__ b1,
                                              const float* __restrict__ w2, const float* __restrict__ b2,
                                              float* __restrict__ t_out,
                                              const float* __restrict__ gnw,
                                              const float* __restrict__ gnb,
                                              f16x2* __restrict__ gpack,
                                              int* __restrict__ deg,
                                              const float* __restrict__ cw1,
                                              const float* __restrict__ cw2,
                                              _Float16* __restrict__ wpack) {
    int bid = blockIdx.x;
    int t = threadIdx.x;
    if (bid == 0) {
        __shared__ float s_time[Bc * TDc];
        __shared__ float s_hid[Bc * Hc];
        for (int i = t; i < Bc * TDc; i += 256) s_time[i] = timev[i];
        __syncthreads();
        int b = t >> 6, j = t & 63;
        float acc = b1[j];
        for (int k = 0; k < TDc; ++k) acc = fmaf(s_time[b * TDc + k], w1[j * TDc + k], acc);
        s_hid[b * Hc + j] = fmaxf(acc, 0.f);
        __syncthreads();
        float acc2 = b2[j];
        for (int k = 0; k < Hc; ++k) acc2 = fmaf(s_hid[b * Hc + k], w2[j * Hc + k], acc2);
        t_out[b * Hc + j] = acc2;
    } else if (bid <= 1024) {
        int i = (bid - 1) * 256 + t;
        f16x2 v;
        v.x = (_Float16)gnw[i];
        v.y = (_Float16)gnb[i];
        gpack[i] = v;
    } else if (bid <= 1040) {
        int i = (bid - 1025) * 256 + t;
        deg[i] = 0;
    } else {
        // fragment-major weight pre-conversion (mapping k_mlp's ds_reads expect)
        int layer = bid - 1041;                     // 0 or 1
        const float* wsrc = layer ? cw2 : cw1;
        #pragma unroll
        for (int v4 = 0; v4 < 4; ++v4) {
            int i4 = t + v4 * 256;                  // 0..1023 vector id
            int j  = i4 >> 4;
            int kq = (i4 & 15) * 4;
            f32x4 v = *(const f32x4*)(wsrc + j * Hc + kq);
            int tt = j >> 4, rr = j & 15, kk = kq >> 4, gg = (kq >> 2) & 3;
            int ln = gg * 16 + rr;
            *(f16x4*)&wpack[(((layer * 4 + tt) * 4 + kk) * 64 + ln) * 4] =
                __builtin_convertvector(v, f16x4);
        }
    }
}

// ---------------- degree count ----------------
__global__ void k_deg(const int* __restrict__ col, int* __restrict__ deg) {
    int e = blockIdx.x * 256 + threadIdx.x;
    atomicAdd(&deg[col[e]], 1);
}

// ---------------- exclusive scan over 4096 degrees + dis = deg^-1/2 ----------------
__global__ __launch_bounds__(1024) void k_scan(const int* __restrict__ deg,
                                               int* __restrict__ offs,
                                               int* __restrict__ cursor,
                                               float* __restrict__ dis) {
    __shared__ int part[1024];
    int t = threadIdx.x;
    int d0 = deg[t * 4], d1 = deg[t * 4 + 1], d2 = deg[t * 4 + 2], d3 = deg[t * 4 + 3];
    part[t] = d0 + d1 + d2 + d3;
    __syncthreads();
    for (int off = 1; off < 1024; off <<= 1) {
        int v = (t >= off) ? part[t - off] : 0;
        __syncthreads();
        part[t] += v;
        __syncthreads();
    }
    int base = (t ? part[t - 1] : 0);
    offs[t * 4]     = base;
    offs[t * 4 + 1] = base + d0;
    offs[t * 4 + 2] = base + d0 + d1;
    offs[t * 4 + 3] = base + d0 + d1 + d2;
    if (t == 1023) offs[4096] = part[1023];
    cursor[t * 4]     = base;
    cursor[t * 4 + 1] = base + d0;
    cursor[t * 4 + 2] = base + d0 + d1;
    cursor[t * 4 + 3] = base + d0 + d1 + d2;
    dis[t * 4]     = d0 > 0 ? rsqrtf((float)d0) : 0.f;
    dis[t * 4 + 1] = d1 > 0 ? rsqrtf((float)d1) : 0.f;
    dis[t * 4 + 2] = d2 > 0 ? rsqrtf((float)d2) : 0.f;
    dis[t * 4 + 3] = d3 > 0 ? rsqrtf((float)d3) : 0.f;
}

// ---------------- CSR fill: csr2 = {src, bits(w)} ----------------
__global__ void k_fill(const int* __restrict__ ei, int* __restrict__ cursor,
                       const float* __restrict__ dis,
                       int2* __restrict__ csr2) {
    int e = blockIdx.x * 256 + threadIdx.x;
    int r = ei[e], c = ei[Ec + e];
    int pos = atomicAdd(&cursor[c], 1);
    int2 v;
    v.x = r;
    v.y = __float_as_int(dis[r] * dis[c]);
    csr2[pos] = v;
}

// ---------------- g12 = {gather(gnw), gather(gnb)} interleaved f16x2 ----------------
__global__ __launch_bounds__(256) void k_gw(const int* __restrict__ offs,
                                            const int2* __restrict__ csr2,
                                            const f16x2* __restrict__ gpack,
                                            f16x2* __restrict__ g12) {
    int wv = threadIdx.x >> 6, lane = threadIdx.x & 63;
    int n = __builtin_amdgcn_readfirstlane(blockIdx.x * 4 + wv);
    int s0 = __builtin_amdgcn_readfirstlane(offs[n]);
    int s1 = __builtin_amdgcn_readfirstlane(offs[n + 1]);
    float a0 = 0.f, a1 = 0.f, a2 = 0.f, a3 = 0.f;
    float b0 = 0.f, b1 = 0.f, b2 = 0.f, b3 = 0.f;
    int i = s0;
    for (; i + 4 <= s1; i += 4) {
        int2 e0 = csr2[i], e1 = csr2[i + 1], e2 = csr2[i + 2], e3 = csr2[i + 3];
        f16x2 v0 = gpack[e0.x * Hc + lane];
        f16x2 v1 = gpack[e1.x * Hc + lane];
        f16x2 v2 = gpack[e2.x * Hc + lane];
        f16x2 v3 = gpack[e3.x * Hc + lane];
        float w0 = __int_as_float(e0.y), w1 = __int_as_float(e1.y);
        float w2 = __int_as_float(e2.y), w3 = __int_as_float(e3.y);
        a0 = fmaf(w0, (float)v0.x, a0); b0 = fmaf(w0, (float)v0.y, b0);
        a1 = fmaf(w1, (float)v1.x, a1); b1 = fmaf(w1, (float)v1.y, b1);
        a2 = fmaf(w2, (float)v2.x, a2); b2 = fmaf(w2, (float)v2.y, b2);
        a3 = fmaf(w3, (float)v3.x, a3); b3 = fmaf(w3, (float)v3.y, b3);
    }
    for (; i < s1; ++i) {
        int2 e = csr2[i];
        f16x2 v = gpack[e.x * Hc + lane];
        float w = __int_as_float(e.y);
        a0 = fmaf(w, (float)v.x, a0); b0 = fmaf(w, (float)v.y, b0);
    }
    f16x2 o;
    o.x = (_Float16)((a0 + a1) + (a2 + a3));
    o.y = (_Float16)((b0 + b1) + (b2 + b3));
    g12[n * Hc + lane] = o;
}

// ---------------- MFMA cond-MLP -> Af[g][n][j][h] fp16 (group-transposed); LN1 stats ----
// ROUND-20 EXACT (session-best k_mlp): 512-thread single-shot, 8 waves share the
// 16.5 KB weight/bias LDS, no c-loop -> no in-loop barrier, straight-line body.
// LDS = 35 KB -> 4 blocks/CU x 8 waves = 32 waves/CU (hardware cap). Weight tile
// staged via 2x global_load_lds (width=16) per thread from pre-converted wpack.
// (Round-21's 768-block 2-shot persistent variant regressed: the in-loop barrier
// convoyed all waves with only 3 blocks/CU of overlap; occupancy fell 56->27%.)
__global__ __launch_bounds__(512) void k_mlp(const float* __restrict__ cond,
                                             const float* __restrict__ x,
                                             const _Float16* __restrict__ wpack,
                                             const float* __restrict__ b1, const float* __restrict__ b2,
                                             const float* __restrict__ gnw,
                                             _Float16* __restrict__ Af, float* __restrict__ part1) {
    __shared__ __align__(16) _Float16 wlds[8192];   // [layer][t][kk][lane][4] = 16 KB
    __shared__ float blds[128];                      // b1 | b2
    __shared__ __align__(16) _Float16 s_h[8][16][72];

    int tid  = threadIdx.x;
    int lane = tid & 63;
    int wv   = tid >> 6;                      // 0..7
    int r = lane & 15, g = lane >> 4;
    int bp = blockIdx.x >> 5;                 // 32 blocks per bp
    int g4 = bp & 7, j6 = bp >> 3;            // bp = g4 + 8*j6
    int nbase = (blockIdx.x & 31) * 128;

    // ---- async weight staging: 16 KB linear copy, 2 chunks of 1 KB per wave ----
    #pragma unroll
    for (int i = 0; i < 2; ++i) {
        int c = wv * 2 + i;                   // chunk 0..15, 1024 B each
        __builtin_amdgcn_global_load_lds(
            (const unsigned int*)((const char*)wpack + c * 1024 + lane * 16),
            (unsigned int*)((char*)wlds + c * 1024), 16, 0, 0);
    }
    if (tid < 64) blds[tid] = b1[tid];
    else if (tid < 128) blds[tid] = b2[tid - 64];
    __syncthreads();   // drains vmcnt -> wlds ready

    int row = blockIdx.x * 128 + wv * 16 + r;
    int n   = row & (Nc - 1);
    int nl = lane >> 3, hq = (lane & 7) * 8;

    // issue all global loads up front
    f32x4 bcf[4], x4[4], gw4[4];
    #pragma unroll
    for (int kk = 0; kk < 4; ++kk)
        bcf[kk] = *(const f32x4*)(cond + (size_t)row * Hc + kk * 16 + 4 * g);
    #pragma unroll
    for (int t = 0; t < 4; ++t) {
        x4[t]  = *(const f32x4*)(x + (size_t)row * Hc + 16 * t + 4 * g);
        gw4[t] = *(const f32x4*)(gnw + n * Hc + 16 * t + 4 * g);
    }
    f16x4 bc[4];
    #pragma unroll
    for (int kk = 0; kk < 4; ++kk) bc[kk] = __builtin_convertvector(bcf[kk], f16x4);
    // layer 1
    f16x4 hB[4];
    #pragma unroll
    for (int t = 0; t < 4; ++t) {
        f32x4 acc = {0.f, 0.f, 0.f, 0.f};
        #pragma unroll
        for (int kk = 0; kk < 4; ++kk) {
            f16x4 a = *(const f16x4*)&wlds[((t * 4 + kk) * 64 + lane) * 4];
            acc = __builtin_amdgcn_mfma_f32_16x16x16f16(a, bc[kk], acc, 0, 0, 0);
        }
        acc += *(const f32x4*)&blds[16 * t + 4 * g];
        f32x4 h;
        h.x = fmaxf(acc.x, 0.f); h.y = fmaxf(acc.y, 0.f);
        h.z = fmaxf(acc.z, 0.f); h.w = fmaxf(acc.w, 0.f);
        hB[t] = __builtin_convertvector(h, f16x4);
    }
    // layer 2 + bias + residual + gnw scale -> fp16 into per-wave LDS tile
    float s = 0.f, ss = 0.f;
    #pragma unroll
    for (int t = 0; t < 4; ++t) {
        f32x4 acc = {0.f, 0.f, 0.f, 0.f};
        #pragma unroll
        for (int kk = 0; kk < 4; ++kk) {
            f16x4 a = *(const f16x4*)&wlds[((16 + t * 4 + kk) * 64 + lane) * 4];
            acc = __builtin_amdgcn_mfma_f32_16x16x16f16(a, hB[kk], acc, 0, 0, 0);
        }
        f32x4 o = acc + *(const f32x4*)&blds[64 + 16 * t + 4 * g] + x4[t];
        s  += o.x + o.y + o.z + o.w;
        ss += o.x * o.x + o.y * o.y + o.z * o.z + o.w * o.w;
        f32x4 av = o * gw4[t];
        *(f16x4*)&s_h[wv][r][16 * t + 4 * g] = __builtin_convertvector(av, f16x4);
    }
    // transpose read-back: wave-private tile (lgkmcnt ordering, no barrier)
    #pragma unroll
    for (int p = 0; p < 2; ++p) {
        f16x8 v = *(const f16x8*)&s_h[wv][p * 8 + nl][hq];
        int nn = nbase + wv * 16 + p * 8 + nl;
        *(f16x8*)(Af + (((size_t)g4 * Nc + nn) * Gg + j6) * Hc + hq) = v;
    }
    for (int off = 32; off; off >>= 1) { s += __shfl_down(s, off); ss += __shfl_down(ss, off); }
    if (lane == 0) {
        int idx = (blockIdx.x & 31) * 8 + wv;  // 0..255
        part1[(bp * 256 + idx) * 2]     = s;
        part1[(bp * 256 + idx) * 2 + 1] = ss;
    }
}

// ---------------- finalize LN stats: mu, rsqrt(var+eps) per bp ----------------
__global__ __launch_bounds__(256) void k_finalize(const float* __restrict__ part, int cnt,
                                                  float* __restrict__ murs) {
    int bp = blockIdx.x;
    float s = 0.f, ss = 0.f;
    for (int i = threadIdx.x; i < cnt; i += 256) {
        s  += part[(bp * cnt + i) * 2];
        ss += part[(bp * cnt + i) * 2 + 1];
    }
    __shared__ float ls[4], lss[4];
    for (int off = 32; off; off >>= 1) { s += __shfl_down(s, off); ss += __shfl_down(ss, off); }
    int w = threadIdx.x >> 6, l = threadIdx.x & 63;
    if (l == 0) { ls[w] = s; lss[w] = ss; }
    __syncthreads();
    if (threadIdx.x == 0) {
        s  = ls[0] + ls[1] + ls[2] + ls[3];
        ss = lss[0] + lss[1] + lss[2] + lss[3];
        float mu = s / (float)NHc;
        float var = ss / (float)NHc - mu * mu;
        murs[bp * 2]     = mu;
        murs[bp * 2 + 1] = rsqrtf(var + EPSc);
    }
}

// ---------------- LGConv gather: 1 n x 6 bp per wave, fp16 dwordx4 lanes ----------------
// Af[g][n][j][h]: one XCD group's slice = 3 MB -> fits 4 MB L2 (bid&7 pin).
// Per edge: ONE global_load_dwordx4 serves 6 bp slices. Lanes 48-63 exec-masked.
// Edge loop 8-deep: 8 loads in flight per batch (avg degree 16 -> 2 batches).
__global__ __launch_bounds__(256) void k_gather(const int* __restrict__ offs,
                                                const int2* __restrict__ csr2,
                                                const _Float16* __restrict__ Af,
                                                const f16x2* __restrict__ g12,
                                                const float* __restrict__ murs,
                                                const float* __restrict__ t_in,
                                                _Float16* __restrict__ h2f,
                                                float* __restrict__ part2) {
    int bid = blockIdx.x;
    int g   = bid & 7;
    int seq = bid >> 3;            // 0..1023
    int wv = threadIdx.x >> 6, lane = threadIdx.x & 63;
    int n  = __builtin_amdgcn_readfirstlane(seq * 4 + wv);
    int jj = lane >> 3;            // 0..7 (6,7 masked off)
    int h0 = (lane & 7) * 8;
    int s0 = __builtin_amdgcn_readfirstlane(offs[n]);
    int s1 = __builtin_amdgcn_readfirstlane(offs[n + 1]);

    if (jj < Gg) {
        const _Float16* base = Af + (size_t)g * (Nc * Gg * Hc) + jj * Hc + h0;
        float acc[8];
        #pragma unroll
        for (int i = 0; i < 8; ++i) acc[i] = 0.f;

        int idx = s0;
        for (; idx + 8 <= s1; idx += 8) {
            int2 e0 = csr2[idx],     e1 = csr2[idx + 1];
            int2 e2 = csr2[idx + 2], e3 = csr2[idx + 3];
            int2 e4 = csr2[idx + 4], e5 = csr2[idx + 5];
            int2 e6 = csr2[idx + 6], e7 = csr2[idx + 7];
            f16x8 v0 = *(const f16x8*)(base + (size_t)e0.x * (Gg * Hc));
            f16x8 v1 = *(const f16x8*)(base + (size_t)e1.x * (Gg * Hc));
            f16x8 v2 = *(const f16x8*)(base + (size_t)e2.x * (Gg * Hc));
            f16x8 v3 = *(const f16x8*)(base + (size_t)e3.x * (Gg * Hc));
            f16x8 v4 = *(const f16x8*)(base + (size_t)e4.x * (Gg * Hc));
            f16x8 v5 = *(const f16x8*)(base + (size_t)e5.x * (Gg * Hc));
            f16x8 v6 = *(const f16x8*)(base + (size_t)e6.x * (Gg * Hc));
            f16x8 v7 = *(const f16x8*)(base + (size_t)e7.x * (Gg * Hc));
            float w0 = __int_as_float(e0.y), w1 = __int_as_float(e1.y);
            float w2 = __int_as_float(e2.y), w3 = __int_as_float(e3.y);
            float w4 = __int_as_float(e4.y), w5 = __int_as_float(e5.y);
            float w6 = __int_as_float(e6.y), w7 = __int_as_float(e7.y);
            #pragma unroll
            for (int i = 0; i < 8; ++i) {
                acc[i] = fmaf(w0, (float)v0[i], acc[i]);
                acc[i] = fmaf(w1, (float)v1[i], acc[i]);
                acc[i] = fmaf(w2, (float)v2[i], acc[i]);
                acc[i] = fmaf(w3, (float)v3[i], acc[i]);
                acc[i] = fmaf(w4, (float)v4[i], acc[i]);
                acc[i] = fmaf(w5, (float)v5[i], acc[i]);
                acc[i] = fmaf(w6, (float)v6[i], acc[i]);
                acc[i] = fmaf(w7, (float)v7[i], acc[i]);
            }
        }
        for (; idx + 4 <= s1; idx += 4) {
            int2 e0 = csr2[idx],     e1 = csr2[idx + 1];
            int2 e2 = csr2[idx + 2], e3 = csr2[idx + 3];
            f16x8 v0 = *(const f16x8*)(base + (size_t)e0.x * (Gg * Hc));
            f16x8 v1 = *(const f16x8*)(base + (size_t)e1.x * (Gg * Hc));
            f16x8 v2 = *(const f16x8*)(base + (size_t)e2.x * (Gg * Hc));
            f16x8 v3 = *(const f16x8*)(base + (size_t)e3.x * (Gg * Hc));
            float w0 = __int_as_float(e0.y), w1 = __int_as_float(e1.y);
            float w2 = __int_as_float(e2.y), w3 = __int_as_float(e3.y);
            #pragma unroll
            for (int i = 0; i < 8; ++i) {
                acc[i] = fmaf(w0, (float)v0[i], acc[i]);
                acc[i] = fmaf(w1, (float)v1[i], acc[i]);
                acc[i] = fmaf(w2, (float)v2[i], acc[i]);
                acc[i] = fmaf(w3, (float)v3[i], acc[i]);
            }
        }
        for (; idx < s1; ++idx) {
            int2 e = csr2[idx];
            f16x8 v = *(const f16x8*)(base + (size_t)e.x * (Gg * Hc));
            float w = __int_as_float(e.y);
            #pragma unroll
            for (int i = 0; i < 8; ++i) acc[i] = fmaf(w, (float)v[i], acc[i]);
        }

        int bp = g + 8 * jj;
        int b  = bp / Pc;
        float mu = murs[bp * 2], rs = murs[bp * 2 + 1];
        const _Float16* gp = (const _Float16*)(g12 + n * Hc + h0);
        f16x8 q0 = *(const f16x8*)gp;        // {g1,g2} pairs for h0..h0+3
        f16x8 q1 = *(const f16x8*)(gp + 8);  // pairs for h0+4..h0+7
        f32x4 tta = *(const f32x4*)(t_in + b * Hc + h0);
        f32x4 ttb = *(const f32x4*)(t_in + b * Hc + h0 + 4);
        f32x4 va, vb;
        va.x = rs * (acc[0] - mu * (float)q0[0]) + (float)q0[1] + tta.x;
        va.y = rs * (acc[1] - mu * (float)q0[2]) + (float)q0[3] + tta.y;
        va.z = rs * (acc[2] - mu * (float)q0[4]) + (float)q0[5] + tta.z;
        va.w = rs * (acc[3] - mu * (float)q0[6]) + (float)q0[7] + tta.w;
        vb.x = rs * (acc[4] - mu * (float)q1[0]) + (float)q1[1] + ttb.x;
        vb.y = rs * (acc[5] - mu * (float)q1[2]) + (float)q1[3] + ttb.y;
        vb.z = rs * (acc[6] - mu * (float)q1[4]) + (float)q1[5] + ttb.z;
        vb.w = rs * (acc[7] - mu * (float)q1[6]) + (float)q1[7] + ttb.w;

        float s  = (va.x + va.y) + (va.z + va.w) + (vb.x + vb.y) + (vb.z + vb.w);
        float ss = va.x * va.x + va.y * va.y + va.z * va.z + va.w * va.w
                 + vb.x * vb.x + vb.y * vb.y + vb.z * vb.z + vb.w * vb.w;
        #pragma unroll
        for (int m = 4; m; m >>= 1) { s += __shfl_xor(s, m); ss += __shfl_xor(ss, m); }

        f16x8 hv;
        hv[0] = (_Float16)va.x; hv[1] = (_Float16)va.y;
        hv[2] = (_Float16)va.z; hv[3] = (_Float16)va.w;
        hv[4] = (_Float16)vb.x; hv[5] = (_Float16)vb.y;
        hv[6] = (_Float16)vb.z; hv[7] = (_Float16)vb.w;
        *(f16x8*)(h2f + (size_t)bp * NHc + n * Hc + h0) = hv;
        if ((lane & 7) == 0) {
            part2[((size_t)bp * Nc + n) * 2]     = s;
            part2[((size_t)bp * Nc + n) * 2 + 1] = ss;
        }
    }
}

// ---------------- apply LN2 + 1x1 conv over P (h2 fp16 in ws) ----------------
__global__ __launch_bounds__(256) void k_conv(const _Float16* __restrict__ h2f,
                                              const float* __restrict__ murs,
                                              const float* __restrict__ tnw, const float* __restrict__ tnb,
                                              const float* __restrict__ cw, const float* __restrict__ cb,
                                              float* __restrict__ out) {
    int tid = blockIdx.x * 256 + threadIdx.x;  // B * NHc/4 threads
    int b  = tid >> 16;           // / (NHc/4)
    int i4 = tid & 65535;
    size_t e0 = (size_t)i4 * 4;
    float4 w4 = *(const float4*)(tnw + e0);
    float4 b4 = *(const float4*)(tnb + e0);
    float v[Pc][4];
    #pragma unroll
    for (int p = 0; p < Pc; ++p) {
        int bp = b * Pc + p;
        float mu = murs[bp * 2], rs = murs[bp * 2 + 1];
        f16x4 h = *(const f16x4*)(h2f + (size_t)bp * NHc + e0);
        v[p][0] = ((float)h.x - mu) * rs * w4.x + b4.x;
        v[p][1] = ((float)h.y - mu) * rs * w4.y + b4.y;
        v[p][2] = ((float)h.z - mu) * rs * w4.z + b4.z;
        v[p][3] = ((float)h.w - mu) * rs * w4.w + b4.w;
    }
    #pragma unroll
    for (int q = 0; q < Pc; ++q) {
        float cbq = cb[q];
        float o0 = cbq, o1 = cbq, o2 = cbq, o3 = cbq;
        #pragma unroll
        for (int p = 0; p < Pc; ++p) {
            float wqp = cw[q * Pc + p];
            o0 = fmaf(v[p][0], wqp, o0);
            o1 = fmaf(v[p][1], wqp, o1);
            o2 = fmaf(v[p][2], wqp, o2);
            o3 = fmaf(v[p][3], wqp, o3);
        }
        float4 o = {o0, o1, o2, o3};
        *(float4*)(out + (size_t)(b * Pc + q) * NHc + e0) = o;
    }
}

extern "C" void kernel_launch(void* const* d_in, const int* in_sizes, int n_in,
                              void* d_out, int out_size, void* d_ws, size_t ws_size,
                              hipStream_t stream) {
    (void)in_sizes; (void)n_in; (void)out_size; (void)ws_size;
    const float* x     = (const float*)d_in[0];
    const int*   ei    = (const int*)  d_in[1];
    const float* timev = (const float*)d_in[2];
    const float* cond  = (const float*)d_in[3];
    const float* tp_w1 = (const float*)d_in[4];
    const float* tp_b1 = (const float*)d_in[5];
    const float* tp_w2 = (const float*)d_in[6];
    const float* tp_b2 = (const float*)d_in[7];
    const float* cp_w1 = (const float*)d_in[8];
    const float* cp_b1 = (const float*)d_in[9];
    const float* cp_w2 = (const float*)d_in[10];
    const float* cp_b2 = (const float*)d_in[11];
    const float* gn_w  = (const float*)d_in[12];
    const float* gn_b  = (const float*)d_in[13];
    const float* tn_w  = (const float*)d_in[14];
    const float* tn_b  = (const float*)d_in[15];
    const float* cw    = (const float*)d_in[16];
    const float* cb    = (const float*)d_in[17];
    float* out = (float*)d_out;

    char* w = (char*)d_ws;
    size_t off = 0;
    auto alloc = [&](size_t bytes) {
        void* p = w + off;
        off = (off + bytes + 255) & ~(size_t)255;
        return p;
    };
    _Float16* Af   = (_Float16*)alloc((size_t)ROWS * Hc * sizeof(_Float16)); // 25 MB
    _Float16* h2f  = (_Float16*)alloc((size_t)ROWS * Hc * sizeof(_Float16)); // 25 MB
    float* part1   = (float*)alloc((size_t)BPc * 256 * 2 * 4);
    float* part2   = (float*)alloc((size_t)BPc * Nc * 2 * 4);
    float* murs1   = (float*)alloc(96 * 4);
    float* murs2   = (float*)alloc(96 * 4);
    float* t_ws    = (float*)alloc(256 * 4);
    float* dis     = (float*)alloc(Nc * 4);
    int2*  csr2    = (int2*)alloc((size_t)Ec * 8);
    f16x2* g12     = (f16x2*)alloc((size_t)NHc * 4);
    f16x2* gpack   = (f16x2*)alloc((size_t)NHc * 4);
    _Float16* wpack = (_Float16*)alloc(8192 * sizeof(_Float16));  // 16 KB frag-major
    int*   deg     = (int*)alloc(Nc * 4);
    int*   offs    = (int*)alloc((Nc + 1) * 4);
    int*   cursor  = (int*)alloc(Nc * 4);

    k_prep<<<1043, 256, 0, stream>>>(timev, tp_w1, tp_b1, tp_w2, tp_b2, t_ws,
                                     gn_w, gn_b, gpack, deg, cp_w1, cp_w2, wpack);
    k_deg<<<Ec / 256, 256, 0, stream>>>(ei + Ec, deg);
    k_scan<<<1, 1024, 0, stream>>>(deg, offs, cursor, dis);
    k_fill<<<Ec / 256, 256, 0, stream>>>(ei, cursor, dis, csr2);
    k_gw<<<Nc / 4, 256, 0, stream>>>(offs, csr2, gpack, g12);
    k_mlp<<<ROWS / 128, 512, 0, stream>>>(cond, x, wpack, cp_b1, cp_b2, gn_w,
                                          Af, part1);
    k_finalize<<<BPc, 256, 0, stream>>>(part1, 256, murs1);
    k_gather<<<8 * 1024, 256, 0, stream>>>(offs, csr2, Af, g12,
                                           murs1, t_ws, h2f, part2);
    k_finalize<<<BPc, 256, 0, stream>>>(part2, Nc, murs2);
    k_conv<<<(Bc * NHc / 4) / 256, 256, 0, stream>>>(h2f, murs2, tn_w, tn_b, cw, cb, out);
}